// Round 1
// baseline (1118.260 us; speedup 1.0000x reference)
//
#include <hip/hip_runtime.h>

#define NU 50000
#define NI 150000
#define NN 200000
#define NE 1250000
#define DD 64
#define NLAYERS 3
#define SCAN_B 1024
#define NB ((NN + SCAN_B - 1) / SCAN_B)   // 196

// ---- init: out[:, 0:64] = concat(user_emb, item_emb) ----
__global__ __launch_bounds__(256) void k_init(const float4* __restrict__ ue,
                                              const float4* __restrict__ ie,
                                              float4* __restrict__ out4) {
  int gid = blockIdx.x * 256 + threadIdx.x;
  if (gid >= NN * 16) return;
  int row = gid >> 4, q = gid & 15;
  float4 v = (row < NU) ? ue[(size_t)row * 16 + q] : ie[(size_t)(row - NU) * 16 + q];
  out4[(size_t)row * 64 + q] = v;  // out row stride = 256 floats = 64 float4
}

// ---- CSR build ----
__global__ __launch_bounds__(256) void k_hist(const int* __restrict__ dst, int* __restrict__ cnt) {
  int e = blockIdx.x * 256 + threadIdx.x;
  if (e < NE) atomicAdd(&cnt[dst[e]], 1);
}

__global__ __launch_bounds__(SCAN_B) void k_scan1(const int* __restrict__ cnt,
                                                  int* __restrict__ local,
                                                  int* __restrict__ btot) {
  __shared__ int sm[SCAN_B];
  int t = threadIdx.x;
  int i = blockIdx.x * SCAN_B + t;
  int v = (i < NN) ? cnt[i] : 0;
  sm[t] = v;
  __syncthreads();
  for (int off = 1; off < SCAN_B; off <<= 1) {
    int x = (t >= off) ? sm[t - off] : 0;
    __syncthreads();
    sm[t] += x;
    __syncthreads();
  }
  if (i < NN) local[i] = sm[t] - v;              // exclusive within block
  if (t == SCAN_B - 1) btot[blockIdx.x] = sm[t]; // block total
}

__global__ __launch_bounds__(256) void k_scan2(int* __restrict__ btot) {
  __shared__ int sm[256];
  int t = threadIdx.x;
  int v = (t < NB) ? btot[t] : 0;
  sm[t] = v;
  __syncthreads();
  for (int off = 1; off < 256; off <<= 1) {
    int x = (t >= off) ? sm[t - off] : 0;
    __syncthreads();
    sm[t] += x;
    __syncthreads();
  }
  if (t < NB) btot[t] = sm[t] - v;  // exclusive block offsets
}

__global__ __launch_bounds__(256) void k_finalize(const int* __restrict__ local,
                                                  const int* __restrict__ btot,
                                                  int* __restrict__ row_start,
                                                  int* __restrict__ cursor) {
  int i = blockIdx.x * 256 + threadIdx.x;
  if (i < NN) {
    int v = local[i] + btot[i / SCAN_B];
    row_start[i] = v;
    cursor[i] = v;
  }
  if (i == 0) row_start[NN] = NE;
}

__global__ __launch_bounds__(256) void k_fill(const int* __restrict__ src,
                                              const int* __restrict__ dst,
                                              const float* __restrict__ w,
                                              int* __restrict__ cursor,
                                              int* __restrict__ csr_src,
                                              float* __restrict__ csr_w) {
  int e = blockIdx.x * 256 + threadIdx.x;
  if (e < NE) {
    int p = atomicAdd(&cursor[dst[e]], 1);
    csr_src[p] = src[e];
    csr_w[p] = w[e];
  }
}

// ---- SpMM: term1[row] = sum_j w_j * e[src_j]; one wave per row ----
__global__ __launch_bounds__(256) void k_spmm(const int* __restrict__ row_start,
                                              const int* __restrict__ csr_src,
                                              const float* __restrict__ csr_w,
                                              const float* __restrict__ eprev, // out + layer*64, row stride 256
                                              float* __restrict__ term1) {
  int gid = blockIdx.x * 256 + threadIdx.x;
  int row = gid >> 6;
  int lane = gid & 63;
  if (row >= NN) return;
  int s0 = row_start[row];
  int s1 = row_start[row + 1];
  float acc = 0.f;
  for (int j = s0; j < s1; ++j) {
    int s = csr_src[j];
    float wj = csr_w[j];
    acc = fmaf(wj, eprev[(size_t)s * 256 + lane], acc);
  }
  term1[(size_t)row * 64 + lane] = acc;
}

// ---- fused: inter = t1@W1 + (t1*e)@W2 + e@W3 + b; leaky; l2norm; store ----
__global__ __launch_bounds__(256) void k_row(const float* __restrict__ term1,
                                             const float* __restrict__ Ws,
                                             const float* __restrict__ bs,
                                             float* __restrict__ out,
                                             int layer) {
  int row = blockIdx.x * 256 + threadIdx.x;
  if (row >= NN) return;
  const float* __restrict__ W1 = Ws + ((size_t)layer * 3 + 0) * 4096;
  const float* __restrict__ W2 = Ws + ((size_t)layer * 3 + 1) * 4096;
  const float* __restrict__ W3 = Ws + ((size_t)layer * 3 + 2) * 4096;
  const float* __restrict__ b1 = bs + ((size_t)layer * 3 + 0) * 64;
  const float* __restrict__ b2 = bs + ((size_t)layer * 3 + 1) * 64;
  const float* __restrict__ b3 = bs + ((size_t)layer * 3 + 2) * 64;

  float acc[DD];
#pragma unroll
  for (int d = 0; d < DD; ++d) acc[d] = b1[d] + b2[d] + b3[d];

  const float4* __restrict__ t4 = reinterpret_cast<const float4*>(term1 + (size_t)row * 64);
  const float4* __restrict__ e4 = reinterpret_cast<const float4*>(out + (size_t)row * 256 + (size_t)layer * 64);

#pragma unroll 1
  for (int kc = 0; kc < 4; ++kc) {
    float4 ta0 = t4[kc * 4 + 0], ta1 = t4[kc * 4 + 1], ta2 = t4[kc * 4 + 2], ta3 = t4[kc * 4 + 3];
    float4 ea0 = e4[kc * 4 + 0], ea1 = e4[kc * 4 + 1], ea2 = e4[kc * 4 + 2], ea3 = e4[kc * 4 + 3];
    float tv[16] = {ta0.x, ta0.y, ta0.z, ta0.w, ta1.x, ta1.y, ta1.z, ta1.w,
                    ta2.x, ta2.y, ta2.z, ta2.w, ta3.x, ta3.y, ta3.z, ta3.w};
    float ev[16] = {ea0.x, ea0.y, ea0.z, ea0.w, ea1.x, ea1.y, ea1.z, ea1.w,
                    ea2.x, ea2.y, ea2.z, ea2.w, ea3.x, ea3.y, ea3.z, ea3.w};
#pragma unroll
    for (int kk = 0; kk < 16; ++kk) {
      float c1 = tv[kk], c3 = ev[kk];
      float c2 = c1 * c3;
      const float* __restrict__ w1r = W1 + (kc * 16 + kk) * 64;
      const float* __restrict__ w2r = W2 + (kc * 16 + kk) * 64;
      const float* __restrict__ w3r = W3 + (kc * 16 + kk) * 64;
#pragma unroll
      for (int d = 0; d < DD; ++d) {
        acc[d] = fmaf(c1, w1r[d], fmaf(c2, w2r[d], fmaf(c3, w3r[d], acc[d])));
      }
    }
  }

  float ss = 0.f;
#pragma unroll
  for (int d = 0; d < DD; ++d) {
    float x = acc[d];
    x = (x >= 0.f) ? x : 0.01f * x;
    acc[d] = x;
    ss = fmaf(x, x, ss);
  }
  float nrm = sqrtf(ss);
  float inv = 1.0f / fmaxf(nrm, 1e-12f);

  float4* __restrict__ op = reinterpret_cast<float4*>(out + (size_t)row * 256 + (size_t)(layer + 1) * 64);
#pragma unroll
  for (int q = 0; q < 16; ++q) {
    float4 v;
    v.x = acc[q * 4 + 0] * inv;
    v.y = acc[q * 4 + 1] * inv;
    v.z = acc[q * 4 + 2] * inv;
    v.w = acc[q * 4 + 3] * inv;
    op[q] = v;
  }
}

extern "C" void kernel_launch(void* const* d_in, const int* in_sizes, int n_in,
                              void* d_out, int out_size, void* d_ws, size_t ws_size,
                              hipStream_t stream) {
  const int* edge_src = (const int*)d_in[0];
  const int* edge_dst = (const int*)d_in[1];
  const float* edge_w = (const float*)d_in[2];
  const float* user_emb = (const float*)d_in[3];
  const float* item_emb = (const float*)d_in[4];
  const float* Ws = (const float*)d_in[5];
  const float* bs = (const float*)d_in[6];
  float* out = (float*)d_out;

  char* w = (char*)d_ws;
  float* term1 = (float*)w;      w += (size_t)NN * 64 * 4;   // 51.2 MB
  int* cnt = (int*)w;            w += (size_t)NN * 4;
  int* local = (int*)w;          w += (size_t)NN * 4;
  int* row_start = (int*)w;      w += (size_t)(NN + 4) * 4;
  int* cursor = (int*)w;         w += (size_t)NN * 4;
  int* btot = (int*)w;           w += 256 * 4;
  int* csr_src = (int*)w;        w += (size_t)NE * 4;
  float* csr_w = (float*)w;      w += (size_t)NE * 4;

  hipMemsetAsync(cnt, 0, (size_t)NN * 4, stream);
  k_init<<<(NN * 16 + 255) / 256, 256, 0, stream>>>(
      (const float4*)user_emb, (const float4*)item_emb, (float4*)out);
  k_hist<<<(NE + 255) / 256, 256, 0, stream>>>(edge_dst, cnt);
  k_scan1<<<NB, SCAN_B, 0, stream>>>(cnt, local, btot);
  k_scan2<<<1, 256, 0, stream>>>(btot);
  k_finalize<<<(NN + 255) / 256, 256, 0, stream>>>(local, btot, row_start, cursor);
  k_fill<<<(NE + 255) / 256, 256, 0, stream>>>(edge_src, edge_dst, edge_w, cursor, csr_src, csr_w);

  for (int layer = 0; layer < NLAYERS; ++layer) {
    k_spmm<<<(NN * 64 + 255) / 256, 256, 0, stream>>>(row_start, csr_src, csr_w,
                                                      out + (size_t)layer * 64, term1);
    k_row<<<(NN + 255) / 256, 256, 0, stream>>>(term1, Ws, bs, out, layer);
  }
}

// Round 2
// 648.356 us; speedup vs baseline: 1.7248x; 1.7248x over previous
//
#include <hip/hip_runtime.h>
#include <hip/hip_bf16.h>

#define NU 50000
#define NI 150000
#define NN 200000
#define NE 1250000
#define DD 64
#define NLAYERS 3
#define SCAN_B 1024
#define NB ((NN + SCAN_B - 1) / SCAN_B)   // 196
#define BT_STRIDE 232                      // bf16 elems; 464 B row: 16B-aligned, 116 words % 32 = 20 -> <=2-way banks

typedef __attribute__((ext_vector_type(8))) short bf16x8;
typedef __attribute__((ext_vector_type(4))) float f32x4;

static __device__ __forceinline__ unsigned short f2b(float x) {
  __hip_bfloat16 h = __float2bfloat16(x);  // RNE
  return *reinterpret_cast<unsigned short*>(&h);
}

static __device__ __forceinline__ bf16x8 pack8(float4 a, float4 b) {
  union { bf16x8 v; unsigned short u[8]; } r;
  r.u[0] = f2b(a.x); r.u[1] = f2b(a.y); r.u[2] = f2b(a.z); r.u[3] = f2b(a.w);
  r.u[4] = f2b(b.x); r.u[5] = f2b(b.y); r.u[6] = f2b(b.z); r.u[7] = f2b(b.w);
  return r.v;
}

static __device__ __forceinline__ float4 m4(float4 a, float4 b) {
  float4 r; r.x = a.x * b.x; r.y = a.y * b.y; r.z = a.z * b.z; r.w = a.w * b.w; return r;
}

// ---- init: out[:, 0:64] = concat(user_emb, item_emb) ----
__global__ __launch_bounds__(256) void k_init(const float4* __restrict__ ue,
                                              const float4* __restrict__ ie,
                                              float4* __restrict__ out4) {
  int gid = blockIdx.x * 256 + threadIdx.x;
  if (gid >= NN * 16) return;
  int row = gid >> 4, q = gid & 15;
  float4 v = (row < NU) ? ue[(size_t)row * 16 + q] : ie[(size_t)(row - NU) * 16 + q];
  out4[(size_t)row * 64 + q] = v;  // out row stride = 256 floats = 64 float4
}

// ---- CSR build ----
__global__ __launch_bounds__(256) void k_hist(const int* __restrict__ dst, int* __restrict__ cnt) {
  int e = blockIdx.x * 256 + threadIdx.x;
  if (e < NE) atomicAdd(&cnt[dst[e]], 1);
}

__global__ __launch_bounds__(SCAN_B) void k_scan1(const int* __restrict__ cnt,
                                                  int* __restrict__ local,
                                                  int* __restrict__ btot) {
  __shared__ int sm[SCAN_B];
  int t = threadIdx.x;
  int i = blockIdx.x * SCAN_B + t;
  int v = (i < NN) ? cnt[i] : 0;
  sm[t] = v;
  __syncthreads();
  for (int off = 1; off < SCAN_B; off <<= 1) {
    int x = (t >= off) ? sm[t - off] : 0;
    __syncthreads();
    sm[t] += x;
    __syncthreads();
  }
  if (i < NN) local[i] = sm[t] - v;              // exclusive within block
  if (t == SCAN_B - 1) btot[blockIdx.x] = sm[t]; // block total
}

__global__ __launch_bounds__(256) void k_scan2(int* __restrict__ btot) {
  __shared__ int sm[256];
  int t = threadIdx.x;
  int v = (t < NB) ? btot[t] : 0;
  sm[t] = v;
  __syncthreads();
  for (int off = 1; off < 256; off <<= 1) {
    int x = (t >= off) ? sm[t - off] : 0;
    __syncthreads();
    sm[t] += x;
    __syncthreads();
  }
  if (t < NB) btot[t] = sm[t] - v;  // exclusive block offsets
}

__global__ __launch_bounds__(256) void k_finalize(const int* __restrict__ local,
                                                  const int* __restrict__ btot,
                                                  int* __restrict__ row_start,
                                                  int* __restrict__ cursor) {
  int i = blockIdx.x * 256 + threadIdx.x;
  if (i < NN) {
    int v = local[i] + btot[i / SCAN_B];
    row_start[i] = v;
    cursor[i] = v;
  }
  if (i == 0) row_start[NN] = NE;
}

__global__ __launch_bounds__(256) void k_fill(const int* __restrict__ src,
                                              const int* __restrict__ dst,
                                              const float* __restrict__ w,
                                              int* __restrict__ cursor,
                                              int* __restrict__ csr_src,
                                              float* __restrict__ csr_w) {
  int e = blockIdx.x * 256 + threadIdx.x;
  if (e < NE) {
    int p = atomicAdd(&cursor[dst[e]], 1);
    csr_src[p] = src[e];
    csr_w[p] = w[e];
  }
}

// ---- SpMM: term1[row] = sum_j w_j * e[src_j]; one wave per row ----
__global__ __launch_bounds__(256) void k_spmm(const int* __restrict__ row_start,
                                              const int* __restrict__ csr_src,
                                              const float* __restrict__ csr_w,
                                              const float* __restrict__ eprev, // out + layer*64, row stride 256
                                              float* __restrict__ term1) {
  int gid = blockIdx.x * 256 + threadIdx.x;
  int row = gid >> 6;
  int lane = gid & 63;
  if (row >= NN) return;
  int s0 = row_start[row];
  int s1 = row_start[row + 1];
  float acc = 0.f;
  for (int j = s0; j < s1; ++j) {
    int s = csr_src[j];
    float wj = csr_w[j];
    acc = fmaf(wj, eprev[(size_t)s * 256 + lane], acc);
  }
  term1[(size_t)row * 64 + lane] = acc;
}

// ---- fused GEMM via MFMA: inter = [t1 | t1*e | e] @ [W1;W2;W3] + b; leaky; l2norm ----
// wave = 16 rows; block = 4 waves = 64 rows; grid = 3125 (200000/64 exact)
__global__ __launch_bounds__(256) void k_row_mfma(const float* __restrict__ term1,
                                                  const float* __restrict__ Ws,
                                                  const float* __restrict__ bs,
                                                  float* __restrict__ out,
                                                  int layer) {
  __shared__ unsigned short Bt[64][BT_STRIDE];  // Bt[n][j] = bf16(Wcat[j][n]), j in [0,192)
  const int tid = threadIdx.x;
  const float* __restrict__ Wl = Ws + (size_t)layer * 3 * 4096;
  {
    int n = tid & 63;
    int jb = (tid >> 6) * 48;
#pragma unroll 4
    for (int j = jb; j < jb + 48; ++j) {
      Bt[n][j] = f2b(Wl[(size_t)j * 64 + n]);  // coalesced over n within a wave
    }
  }
  __syncthreads();

  const int l = tid & 63;
  const int wv = tid >> 6;
  const int g = l >> 4;    // A: k-group; D: row-group
  const int li = l & 15;   // A: row; D: col
  const int rowbase = blockIdx.x * 64 + wv * 16;
  const int r = rowbase + li;

  // A fragments: lane holds 8 contiguous k at k0 = 8*g (lo half) / 32+8*g (hi half)
  const float4* __restrict__ t1p = reinterpret_cast<const float4*>(term1 + (size_t)r * 64);
  const float4* __restrict__ ep  = reinterpret_cast<const float4*>(out + (size_t)r * 256 + (size_t)layer * 64);
  float4 ta0 = t1p[2 * g], ta1 = t1p[2 * g + 1];
  float4 tb0 = t1p[8 + 2 * g], tb1 = t1p[8 + 2 * g + 1];
  float4 ea0 = ep[2 * g], ea1 = ep[2 * g + 1];
  float4 eb0 = ep[8 + 2 * g], eb1 = ep[8 + 2 * g + 1];

  bf16x8 Afr[6];
  Afr[0] = pack8(ta0, ta1);                // k   0..63 : t1
  Afr[1] = pack8(tb0, tb1);
  Afr[2] = pack8(m4(ta0, ea0), m4(ta1, ea1));  // k  64..127: t1*e
  Afr[3] = pack8(m4(tb0, eb0), m4(tb1, eb1));
  Afr[4] = pack8(ea0, ea1);                // k 128..191: e
  Afr[5] = pack8(eb0, eb1);

  // acc init = b1[n]+b2[n]+b3[n] (bias depends only on output col n)
  const float* __restrict__ bsl = bs + (size_t)layer * 3 * 64;
  f32x4 acc[4];
#pragma unroll
  for (int f = 0; f < 4; ++f) {
    int n = f * 16 + li;
    float bv = bsl[n] + bsl[64 + n] + bsl[128 + n];
    acc[f] = (f32x4){bv, bv, bv, bv};
  }

#pragma unroll
  for (int s = 0; s < 6; ++s) {
#pragma unroll
    for (int f = 0; f < 4; ++f) {
      // B frag: col n = f*16+li, k = s*32 + 8*g .. +8 ; 16B-aligned ds_read_b128
      const bf16x8 Bf = *reinterpret_cast<const bf16x8*>(&Bt[f * 16 + li][s * 32 + 8 * g]);
      acc[f] = __builtin_amdgcn_mfma_f32_16x16x32_bf16(Afr[s], Bf, acc[f], 0, 0, 0);
    }
  }

  // epilogue: leaky relu, row L2 norm (row = rowbase + 4*g + reg, col = f*16 + li)
  float p[4];
#pragma unroll
  for (int reg = 0; reg < 4; ++reg) {
    float ssum = 0.f;
#pragma unroll
    for (int f = 0; f < 4; ++f) {
      float x = acc[f][reg];
      x = (x >= 0.f) ? x : 0.01f * x;
      acc[f][reg] = x;
      ssum = fmaf(x, x, ssum);
    }
    p[reg] = ssum;
  }
#pragma unroll
  for (int off = 1; off < 16; off <<= 1) {
#pragma unroll
    for (int reg = 0; reg < 4; ++reg) p[reg] += __shfl_xor(p[reg], off, 64);
  }
  float inv[4];
#pragma unroll
  for (int reg = 0; reg < 4; ++reg) inv[reg] = 1.0f / fmaxf(sqrtf(p[reg]), 1e-12f);

  float* __restrict__ ob = out + (size_t)(layer + 1) * 64;
#pragma unroll
  for (int reg = 0; reg < 4; ++reg) {
#pragma unroll
    for (int f = 0; f < 4; ++f) {
      ob[(size_t)(rowbase + 4 * g + reg) * 256 + f * 16 + li] = acc[f][reg] * inv[reg];
    }
  }
}

extern "C" void kernel_launch(void* const* d_in, const int* in_sizes, int n_in,
                              void* d_out, int out_size, void* d_ws, size_t ws_size,
                              hipStream_t stream) {
  const int* edge_src = (const int*)d_in[0];
  const int* edge_dst = (const int*)d_in[1];
  const float* edge_w = (const float*)d_in[2];
  const float* user_emb = (const float*)d_in[3];
  const float* item_emb = (const float*)d_in[4];
  const float* Ws = (const float*)d_in[5];
  const float* bs = (const float*)d_in[6];
  float* out = (float*)d_out;

  char* w = (char*)d_ws;
  float* term1 = (float*)w;      w += (size_t)NN * 64 * 4;   // 51.2 MB
  int* cnt = (int*)w;            w += (size_t)NN * 4;
  int* local = (int*)w;          w += (size_t)NN * 4;
  int* row_start = (int*)w;      w += (size_t)(NN + 4) * 4;
  int* cursor = (int*)w;         w += (size_t)NN * 4;
  int* btot = (int*)w;           w += 256 * 4;
  int* csr_src = (int*)w;        w += (size_t)NE * 4;
  float* csr_w = (float*)w;      w += (size_t)NE * 4;

  hipMemsetAsync(cnt, 0, (size_t)NN * 4, stream);
  k_init<<<(NN * 16 + 255) / 256, 256, 0, stream>>>(
      (const float4*)user_emb, (const float4*)item_emb, (float4*)out);
  k_hist<<<(NE + 255) / 256, 256, 0, stream>>>(edge_dst, cnt);
  k_scan1<<<NB, SCAN_B, 0, stream>>>(cnt, local, btot);
  k_scan2<<<1, 256, 0, stream>>>(btot);
  k_finalize<<<(NN + 255) / 256, 256, 0, stream>>>(local, btot, row_start, cursor);
  k_fill<<<(NE + 255) / 256, 256, 0, stream>>>(edge_src, edge_dst, edge_w, cursor, csr_src, csr_w);

  for (int layer = 0; layer < NLAYERS; ++layer) {
    k_spmm<<<(NN * 64 + 255) / 256, 256, 0, stream>>>(row_start, csr_src, csr_w,
                                                      out + (size_t)layer * 64, term1);
    k_row_mfma<<<NN / 64, 256, 0, stream>>>(term1, Ws, bs, out, layer);
  }
}

// Round 3
// 454.742 us; speedup vs baseline: 2.4591x; 1.4258x over previous
//
#include <hip/hip_runtime.h>
#include <hip/hip_bf16.h>

#define NU 50000
#define NI 150000
#define NN 200000
#define NE 1250000
#define DD 64
#define NLAYERS 3
#define SCAN_B 1024
#define NB ((NN + SCAN_B - 1) / SCAN_B)   // 196
#define BT_STRIDE 232                      // bf16 elems; 464 B row: 16B-aligned, 116 words % 32 = 20 -> <=2-way banks

typedef __attribute__((ext_vector_type(8))) short bf16x8;
typedef __attribute__((ext_vector_type(4))) float f32x4;

static __device__ __forceinline__ unsigned short f2b(float x) {
  __hip_bfloat16 h = __float2bfloat16(x);  // RNE
  return *reinterpret_cast<unsigned short*>(&h);
}

static __device__ __forceinline__ unsigned int pack2(float lo, float hi) {
  return (unsigned int)f2b(lo) | ((unsigned int)f2b(hi) << 16);
}

static __device__ __forceinline__ bf16x8 pack8(float4 a, float4 b) {
  union { bf16x8 v; unsigned short u[8]; } r;
  r.u[0] = f2b(a.x); r.u[1] = f2b(a.y); r.u[2] = f2b(a.z); r.u[3] = f2b(a.w);
  r.u[4] = f2b(b.x); r.u[5] = f2b(b.y); r.u[6] = f2b(b.z); r.u[7] = f2b(b.w);
  return r.v;
}

static __device__ __forceinline__ float4 m4(float4 a, float4 b) {
  float4 r; r.x = a.x * b.x; r.y = a.y * b.y; r.z = a.z * b.z; r.w = a.w * b.w; return r;
}

// ---- init: out[:, 0:64] = concat(user_emb, item_emb); also bf16 copy ----
__global__ __launch_bounds__(256) void k_init(const float4* __restrict__ ue,
                                              const float4* __restrict__ ie,
                                              float4* __restrict__ out4,
                                              uint2* __restrict__ ebf2) {
  int gid = blockIdx.x * 256 + threadIdx.x;
  if (gid >= NN * 16) return;
  int row = gid >> 4, q = gid & 15;
  float4 v = (row < NU) ? ue[(size_t)row * 16 + q] : ie[(size_t)(row - NU) * 16 + q];
  out4[(size_t)row * 64 + q] = v;  // out row stride = 256 floats = 64 float4
  uint2 b; b.x = pack2(v.x, v.y); b.y = pack2(v.z, v.w);
  ebf2[(size_t)row * 16 + q] = b;  // ebf row = 64 bf16 = 16 uint2
}

// ---- CSR build ----
__global__ __launch_bounds__(256) void k_hist(const int* __restrict__ dst, int* __restrict__ cnt) {
  int e = blockIdx.x * 256 + threadIdx.x;
  if (e < NE) atomicAdd(&cnt[dst[e]], 1);
}

__global__ __launch_bounds__(SCAN_B) void k_scan1(const int* __restrict__ cnt,
                                                  int* __restrict__ local,
                                                  int* __restrict__ btot) {
  __shared__ int sm[SCAN_B];
  int t = threadIdx.x;
  int i = blockIdx.x * SCAN_B + t;
  int v = (i < NN) ? cnt[i] : 0;
  sm[t] = v;
  __syncthreads();
  for (int off = 1; off < SCAN_B; off <<= 1) {
    int x = (t >= off) ? sm[t - off] : 0;
    __syncthreads();
    sm[t] += x;
    __syncthreads();
  }
  if (i < NN) local[i] = sm[t] - v;              // exclusive within block
  if (t == SCAN_B - 1) btot[blockIdx.x] = sm[t]; // block total
}

__global__ __launch_bounds__(256) void k_scan2(int* __restrict__ btot) {
  __shared__ int sm[256];
  int t = threadIdx.x;
  int v = (t < NB) ? btot[t] : 0;
  sm[t] = v;
  __syncthreads();
  for (int off = 1; off < 256; off <<= 1) {
    int x = (t >= off) ? sm[t - off] : 0;
    __syncthreads();
    sm[t] += x;
    __syncthreads();
  }
  if (t < NB) btot[t] = sm[t] - v;  // exclusive block offsets
}

__global__ __launch_bounds__(256) void k_finalize(const int* __restrict__ local,
                                                  const int* __restrict__ btot,
                                                  int* __restrict__ row_start,
                                                  int* __restrict__ cursor) {
  int i = blockIdx.x * 256 + threadIdx.x;
  if (i < NN) {
    int v = local[i] + btot[i / SCAN_B];
    row_start[i] = v;
    cursor[i] = v;
  }
  if (i == 0) row_start[NN] = NE;
}

__global__ __launch_bounds__(256) void k_fill(const int* __restrict__ src,
                                              const int* __restrict__ dst,
                                              const float* __restrict__ w,
                                              int* __restrict__ cursor,
                                              int2* __restrict__ csr_pack) {
  int e = blockIdx.x * 256 + threadIdx.x;
  if (e < NE) {
    int p = atomicAdd(&cursor[dst[e]], 1);
    int2 pk; pk.x = src[e]; pk.y = __float_as_int(w[e]);
    csr_pack[p] = pk;
  }
}

// ---- SpMM v2: wave per row; lane = 32*h + c; 2 edges/iter, clamped 8-edge rounds ----
__global__ __launch_bounds__(256) void k_spmm(const int* __restrict__ row_start,
                                              const int2* __restrict__ csr_pack,
                                              const unsigned int* __restrict__ ebf, // [NN][32] uint (64 bf16)
                                              float* __restrict__ term1) {
  int gid = blockIdx.x * 256 + threadIdx.x;
  int row = gid >> 6;
  if (row >= NN) return;
  int l = gid & 63;
  int h = l >> 5;   // which edge of the pair
  int c = l & 31;   // col-pair index: cols 2c, 2c+1
  int s0 = row_start[row];
  int s1 = row_start[row + 1];
  float a0 = 0.f, a1 = 0.f;
  for (int base = s0; base < s1; base += 8) {
    int j0 = base + 0 + h, j1 = base + 2 + h, j2 = base + 4 + h, j3 = base + 6 + h;
    int2 p0 = csr_pack[j0 < s1 ? j0 : s0];
    int2 p1 = csr_pack[j1 < s1 ? j1 : s0];
    int2 p2 = csr_pack[j2 < s1 ? j2 : s0];
    int2 p3 = csr_pack[j3 < s1 ? j3 : s0];
    unsigned int v0 = ebf[(size_t)p0.x * 32 + c];
    unsigned int v1 = ebf[(size_t)p1.x * 32 + c];
    unsigned int v2 = ebf[(size_t)p2.x * 32 + c];
    unsigned int v3 = ebf[(size_t)p3.x * 32 + c];
    float w0 = (j0 < s1) ? __int_as_float(p0.y) : 0.f;
    float w1 = (j1 < s1) ? __int_as_float(p1.y) : 0.f;
    float w2 = (j2 < s1) ? __int_as_float(p2.y) : 0.f;
    float w3 = (j3 < s1) ? __int_as_float(p3.y) : 0.f;
    a0 = fmaf(w0, __uint_as_float(v0 << 16), a0);
    a1 = fmaf(w0, __uint_as_float(v0 & 0xffff0000u), a1);
    a0 = fmaf(w1, __uint_as_float(v1 << 16), a0);
    a1 = fmaf(w1, __uint_as_float(v1 & 0xffff0000u), a1);
    a0 = fmaf(w2, __uint_as_float(v2 << 16), a0);
    a1 = fmaf(w2, __uint_as_float(v2 & 0xffff0000u), a1);
    a0 = fmaf(w3, __uint_as_float(v3 << 16), a0);
    a1 = fmaf(w3, __uint_as_float(v3 & 0xffff0000u), a1);
  }
  a0 += __shfl_xor(a0, 32, 64);
  a1 += __shfl_xor(a1, 32, 64);
  if (h == 0) {
    float2 st; st.x = a0; st.y = a1;
    reinterpret_cast<float2*>(term1 + (size_t)row * 64)[c] = st;
  }
}

// ---- fused GEMM via MFMA: inter = [t1 | t1*e | e] @ [W1;W2;W3] + b; leaky; l2norm ----
// wave = 16 rows; block = 4 waves = 64 rows; grid = 3125 (200000/64 exact)
__global__ __launch_bounds__(256) void k_row_mfma(const float* __restrict__ term1,
                                                  const float* __restrict__ Ws,
                                                  const float* __restrict__ bs,
                                                  float* __restrict__ out,
                                                  unsigned short* __restrict__ ebf_next, // bf16 copy of new e (or null-skip via flag)
                                                  int layer) {
  __shared__ unsigned short Bt[64][BT_STRIDE];  // Bt[n][j] = bf16(Wcat[j][n]), j in [0,192)
  const int tid = threadIdx.x;
  const float* __restrict__ Wl = Ws + (size_t)layer * 3 * 4096;
  {
    int n = tid & 63;
    int jb = (tid >> 6) * 48;
#pragma unroll 4
    for (int j = jb; j < jb + 48; ++j) {
      Bt[n][j] = f2b(Wl[(size_t)j * 64 + n]);  // coalesced over n within a wave
    }
  }
  __syncthreads();

  const int l = tid & 63;
  const int wv = tid >> 6;
  const int g = l >> 4;    // A: k-group; D: row-group
  const int li = l & 15;   // A: row; D: col
  const int rowbase = blockIdx.x * 64 + wv * 16;
  const int r = rowbase + li;

  // A fragments: lane holds 8 contiguous k at k0 = 8*g (lo half) / 32+8*g (hi half)
  const float4* __restrict__ t1p = reinterpret_cast<const float4*>(term1 + (size_t)r * 64);
  const float4* __restrict__ ep  = reinterpret_cast<const float4*>(out + (size_t)r * 256 + (size_t)layer * 64);
  float4 ta0 = t1p[2 * g], ta1 = t1p[2 * g + 1];
  float4 tb0 = t1p[8 + 2 * g], tb1 = t1p[8 + 2 * g + 1];
  float4 ea0 = ep[2 * g], ea1 = ep[2 * g + 1];
  float4 eb0 = ep[8 + 2 * g], eb1 = ep[8 + 2 * g + 1];

  bf16x8 Afr[6];
  Afr[0] = pack8(ta0, ta1);                // k   0..63 : t1
  Afr[1] = pack8(tb0, tb1);
  Afr[2] = pack8(m4(ta0, ea0), m4(ta1, ea1));  // k  64..127: t1*e
  Afr[3] = pack8(m4(tb0, eb0), m4(tb1, eb1));
  Afr[4] = pack8(ea0, ea1);                // k 128..191: e
  Afr[5] = pack8(eb0, eb1);

  // acc init = b1[n]+b2[n]+b3[n] (bias depends only on output col n)
  const float* __restrict__ bsl = bs + (size_t)layer * 3 * 64;
  f32x4 acc[4];
#pragma unroll
  for (int f = 0; f < 4; ++f) {
    int n = f * 16 + li;
    float bv = bsl[n] + bsl[64 + n] + bsl[128 + n];
    acc[f] = (f32x4){bv, bv, bv, bv};
  }

#pragma unroll
  for (int s = 0; s < 6; ++s) {
#pragma unroll
    for (int f = 0; f < 4; ++f) {
      // B frag: col n = f*16+li, k = s*32 + 8*g .. +8 ; 16B-aligned ds_read_b128
      const bf16x8 Bf = *reinterpret_cast<const bf16x8*>(&Bt[f * 16 + li][s * 32 + 8 * g]);
      acc[f] = __builtin_amdgcn_mfma_f32_16x16x32_bf16(Afr[s], Bf, acc[f], 0, 0, 0);
    }
  }

  // epilogue: leaky relu, row L2 norm (row = rowbase + 4*g + reg, col = f*16 + li)
  float p[4];
#pragma unroll
  for (int reg = 0; reg < 4; ++reg) {
    float ssum = 0.f;
#pragma unroll
    for (int f = 0; f < 4; ++f) {
      float x = acc[f][reg];
      x = (x >= 0.f) ? x : 0.01f * x;
      acc[f][reg] = x;
      ssum = fmaf(x, x, ssum);
    }
    p[reg] = ssum;
  }
#pragma unroll
  for (int off = 1; off < 16; off <<= 1) {
#pragma unroll
    for (int reg = 0; reg < 4; ++reg) p[reg] += __shfl_xor(p[reg], off, 64);
  }
  float inv[4];
#pragma unroll
  for (int reg = 0; reg < 4; ++reg) inv[reg] = 1.0f / fmaxf(sqrtf(p[reg]), 1e-12f);

  float* __restrict__ ob = out + (size_t)(layer + 1) * 64;
  const bool wbf = (layer + 1) < NLAYERS;
#pragma unroll
  for (int reg = 0; reg < 4; ++reg) {
#pragma unroll
    for (int f = 0; f < 4; ++f) {
      float val = acc[f][reg] * inv[reg];
      ob[(size_t)(rowbase + 4 * g + reg) * 256 + f * 16 + li] = val;
      if (wbf) ebf_next[(size_t)(rowbase + 4 * g + reg) * 64 + f * 16 + li] = f2b(val);
    }
  }
}

extern "C" void kernel_launch(void* const* d_in, const int* in_sizes, int n_in,
                              void* d_out, int out_size, void* d_ws, size_t ws_size,
                              hipStream_t stream) {
  const int* edge_src = (const int*)d_in[0];
  const int* edge_dst = (const int*)d_in[1];
  const float* edge_w = (const float*)d_in[2];
  const float* user_emb = (const float*)d_in[3];
  const float* item_emb = (const float*)d_in[4];
  const float* Ws = (const float*)d_in[5];
  const float* bs = (const float*)d_in[6];
  float* out = (float*)d_out;

  char* w = (char*)d_ws;
  float* term1 = (float*)w;       w += (size_t)NN * 64 * 4;   // 51.2 MB
  unsigned int* ebf = (unsigned int*)w; w += (size_t)NN * 32 * 4;  // 25.6 MB
  int2* csr_pack = (int2*)w;      w += (size_t)NE * 8;        // 10 MB
  int* cnt = (int*)w;             w += (size_t)NN * 4;
  int* local = (int*)w;           w += (size_t)NN * 4;
  int* row_start = (int*)w;       w += (size_t)(NN + 4) * 4;
  int* cursor = (int*)w;          w += (size_t)NN * 4;
  int* btot = (int*)w;            w += 256 * 4;

  hipMemsetAsync(cnt, 0, (size_t)NN * 4, stream);
  k_init<<<(NN * 16 + 255) / 256, 256, 0, stream>>>(
      (const float4*)user_emb, (const float4*)item_emb, (float4*)out, (uint2*)ebf);
  k_hist<<<(NE + 255) / 256, 256, 0, stream>>>(edge_dst, cnt);
  k_scan1<<<NB, SCAN_B, 0, stream>>>(cnt, local, btot);
  k_scan2<<<1, 256, 0, stream>>>(btot);
  k_finalize<<<(NN + 255) / 256, 256, 0, stream>>>(local, btot, row_start, cursor);
  k_fill<<<(NE + 255) / 256, 256, 0, stream>>>(edge_src, edge_dst, edge_w, cursor, csr_pack);

  for (int layer = 0; layer < NLAYERS; ++layer) {
    k_spmm<<<(NN * 64 + 255) / 256, 256, 0, stream>>>(row_start, csr_pack, ebf, term1);
    k_row_mfma<<<NN / 64, 256, 0, stream>>>(term1, Ws, bs, out, (unsigned short*)ebf, layer);
  }
}

// Round 4
// 416.060 us; speedup vs baseline: 2.6877x; 1.0930x over previous
//
#include <hip/hip_runtime.h>
#include <hip/hip_bf16.h>

#define NU 50000
#define NI 150000
#define NN 200000
#define NE 1250000
#define DD 64
#define NLAYERS 3
#define SCAN_B 1024
#define NB ((NN + SCAN_B - 1) / SCAN_B)   // 196
#define BT_STRIDE 232                      // bf16; 464B row: 16B-aligned, <=2-way banks
#define T1_STRIDE 72                       // bf16; 144B row: 16B-aligned, 2-way banks (free)

typedef __attribute__((ext_vector_type(8))) short bf16x8;
typedef __attribute__((ext_vector_type(4))) float f32x4;

static __device__ __forceinline__ unsigned short f2b(float x) {
  __hip_bfloat16 h = __float2bfloat16(x);  // RNE
  return *reinterpret_cast<unsigned short*>(&h);
}

static __device__ __forceinline__ unsigned int pack2(float lo, float hi) {
  return (unsigned int)f2b(lo) | ((unsigned int)f2b(hi) << 16);
}

static __device__ __forceinline__ float blo(unsigned int u) { return __uint_as_float(u << 16); }
static __device__ __forceinline__ float bhi(unsigned int u) { return __uint_as_float(u & 0xffff0000u); }

// elementwise bf16x8 * bf16x8 -> bf16x8 (via f32)
static __device__ __forceinline__ bf16x8 mulbf8(bf16x8 a, bf16x8 b) {
  union { bf16x8 v; unsigned int u[4]; } A, B, R;
  A.v = a; B.v = b;
#pragma unroll
  for (int i = 0; i < 4; ++i) {
    R.u[i] = pack2(blo(A.u[i]) * blo(B.u[i]), bhi(A.u[i]) * bhi(B.u[i]));
  }
  return R.v;
}

// ---- zero cnt (replaces slow in-graph hipMemsetAsync) ----
__global__ __launch_bounds__(256) void k_zero(int* __restrict__ p) {
  int i = blockIdx.x * 256 + threadIdx.x;
  if (i < NN) p[i] = 0;
}

// ---- init: out[:, 0:64] = concat(user_emb, item_emb); also bf16 copy ----
__global__ __launch_bounds__(256) void k_init(const float4* __restrict__ ue,
                                              const float4* __restrict__ ie,
                                              float4* __restrict__ out4,
                                              uint2* __restrict__ ebf2) {
  int gid = blockIdx.x * 256 + threadIdx.x;
  if (gid >= NN * 16) return;
  int row = gid >> 4, q = gid & 15;
  float4 v = (row < NU) ? ue[(size_t)row * 16 + q] : ie[(size_t)(row - NU) * 16 + q];
  out4[(size_t)row * 64 + q] = v;  // out row stride = 256 floats = 64 float4
  uint2 b; b.x = pack2(v.x, v.y); b.y = pack2(v.z, v.w);
  ebf2[(size_t)row * 16 + q] = b;  // ebf row = 64 bf16 = 16 uint2
}

// ---- CSR build ----
__global__ __launch_bounds__(256) void k_hist(const int* __restrict__ dst, int* __restrict__ cnt) {
  int e = blockIdx.x * 256 + threadIdx.x;
  if (e < NE) atomicAdd(&cnt[dst[e]], 1);
}

__global__ __launch_bounds__(SCAN_B) void k_scan1(const int* __restrict__ cnt,
                                                  int* __restrict__ local,
                                                  int* __restrict__ btot) {
  __shared__ int sm[SCAN_B];
  int t = threadIdx.x;
  int i = blockIdx.x * SCAN_B + t;
  int v = (i < NN) ? cnt[i] : 0;
  sm[t] = v;
  __syncthreads();
  for (int off = 1; off < SCAN_B; off <<= 1) {
    int x = (t >= off) ? sm[t - off] : 0;
    __syncthreads();
    sm[t] += x;
    __syncthreads();
  }
  if (i < NN) local[i] = sm[t] - v;              // exclusive within block
  if (t == SCAN_B - 1) btot[blockIdx.x] = sm[t]; // block total
}

__global__ __launch_bounds__(256) void k_scan2(int* __restrict__ btot) {
  __shared__ int sm[256];
  int t = threadIdx.x;
  int v = (t < NB) ? btot[t] : 0;
  sm[t] = v;
  __syncthreads();
  for (int off = 1; off < 256; off <<= 1) {
    int x = (t >= off) ? sm[t - off] : 0;
    __syncthreads();
    sm[t] += x;
    __syncthreads();
  }
  if (t < NB) btot[t] = sm[t] - v;  // exclusive block offsets
}

__global__ __launch_bounds__(256) void k_finalize(const int* __restrict__ local,
                                                  const int* __restrict__ btot,
                                                  int* __restrict__ row_start,
                                                  int* __restrict__ cursor) {
  int i = blockIdx.x * 256 + threadIdx.x;
  if (i < NN) {
    int v = local[i] + btot[i / SCAN_B];
    row_start[i] = v;
    cursor[i] = v;
  }
  if (i == 0) row_start[NN] = NE;
}

__global__ __launch_bounds__(256) void k_fill(const int* __restrict__ src,
                                              const int* __restrict__ dst,
                                              const float* __restrict__ w,
                                              int* __restrict__ cursor,
                                              int2* __restrict__ csr_pack) {
  int e = blockIdx.x * 256 + threadIdx.x;
  if (e < NE) {
    int p = atomicAdd(&cursor[dst[e]], 1);
    int2 pk; pk.x = src[e]; pk.y = __float_as_int(w[e]);
    csr_pack[p] = pk;
  }
}

// ---- fused layer: SpMM (wave per row, 16 rows/wave) -> LDS t1 -> MFMA GEMM -> epilogue ----
// block = 256 thr = 4 waves = 64 rows; grid = 3125
__global__ __launch_bounds__(256) void k_layer(const int* __restrict__ row_start,
                                               const int2* __restrict__ csr_pack,
                                               const unsigned int* __restrict__ ebf,   // [NN][32] uint (64 bf16/row)
                                               const float* __restrict__ Ws,
                                               const float* __restrict__ bs,
                                               float* __restrict__ out,
                                               unsigned short* __restrict__ ebf_next,
                                               int layer, int wbf) {
  __shared__ unsigned short Bt[64][BT_STRIDE];     // Bt[n][j] = bf16(Wcat[j][n])
  __shared__ unsigned short t1s[4][16][T1_STRIDE]; // per-wave t1 tile, bf16

  const int tid = threadIdx.x;
  const float* __restrict__ Wl = Ws + (size_t)layer * 3 * 4096;
  {
    int n = tid & 63;
    int jb = (tid >> 6) * 48;
#pragma unroll 4
    for (int j = jb; j < jb + 48; ++j) Bt[n][j] = f2b(Wl[(size_t)j * 64 + n]);
  }
  __syncthreads();

  const int l = tid & 63;
  const int wv = tid >> 6;
  const int rbase = blockIdx.x * 64 + wv * 16;

  // ================= SpMM phase (wave-local) =================
  {
    const int h = l >> 5, c = l & 31;
    int rs = row_start[rbase + (l < 16 ? l : 16)];  // lanes 0..15: row offsets; lanes >=16: end

    int2 q0, q1, q2, q3;
    {
      int b = __shfl(rs, 0, 64), e = __shfl(rs, 1, 64);
      int j;
      j = b + 0 + h; q0 = csr_pack[j < e ? j : 0];
      j = b + 2 + h; q1 = csr_pack[j < e ? j : 0];
      j = b + 4 + h; q2 = csr_pack[j < e ? j : 0];
      j = b + 6 + h; q3 = csr_pack[j < e ? j : 0];
    }
#pragma unroll 1
    for (int rr = 0; rr < 16; ++rr) {
      int s0 = __shfl(rs, rr, 64), s1 = __shfl(rs, rr + 1, 64);
      float a0 = 0.f, a1 = 0.f;
      unsigned int v0 = 0, v1 = 0, v2 = 0, v3 = 0;
      float w0 = 0.f, w1 = 0.f, w2 = 0.f, w3 = 0.f;
      const bool any = s0 < s1;  // wave-uniform
      if (any) {
        v0 = ebf[(size_t)q0.x * 32 + c];
        v1 = ebf[(size_t)q1.x * 32 + c];
        v2 = ebf[(size_t)q2.x * 32 + c];
        v3 = ebf[(size_t)q3.x * 32 + c];
        w0 = (s0 + 0 + h < s1) ? __int_as_float(q0.y) : 0.f;
        w1 = (s0 + 2 + h < s1) ? __int_as_float(q1.y) : 0.f;
        w2 = (s0 + 4 + h < s1) ? __int_as_float(q2.y) : 0.f;
        w3 = (s0 + 6 + h < s1) ? __int_as_float(q3.y) : 0.f;
      }
      // prefetch next row's round-0 CSR while gathers are in flight
      int2 n0, n1, n2, n3;
      {
        int b = __shfl(rs, rr + 1, 64), e = __shfl(rs, rr + 2 <= 16 ? rr + 2 : 16, 64);
        int j;
        j = b + 0 + h; n0 = csr_pack[j < e ? j : 0];
        j = b + 2 + h; n1 = csr_pack[j < e ? j : 0];
        j = b + 4 + h; n2 = csr_pack[j < e ? j : 0];
        j = b + 6 + h; n3 = csr_pack[j < e ? j : 0];
      }
      if (any) {
        a0 = fmaf(w0, blo(v0), a0); a1 = fmaf(w0, bhi(v0), a1);
        a0 = fmaf(w1, blo(v1), a0); a1 = fmaf(w1, bhi(v1), a1);
        a0 = fmaf(w2, blo(v2), a0); a1 = fmaf(w2, bhi(v2), a1);
        a0 = fmaf(w3, blo(v3), a0); a1 = fmaf(w3, bhi(v3), a1);
        for (int base = s0 + 8; base < s1; base += 8) {  // rare extra rounds
          int2 t0, t1_, t2, t3;
          int j;
          j = base + 0 + h; t0 = csr_pack[j < s1 ? j : 0];
          j = base + 2 + h; t1_ = csr_pack[j < s1 ? j : 0];
          j = base + 4 + h; t2 = csr_pack[j < s1 ? j : 0];
          j = base + 6 + h; t3 = csr_pack[j < s1 ? j : 0];
          unsigned int u0 = ebf[(size_t)t0.x * 32 + c];
          unsigned int u1 = ebf[(size_t)t1_.x * 32 + c];
          unsigned int u2 = ebf[(size_t)t2.x * 32 + c];
          unsigned int u3 = ebf[(size_t)t3.x * 32 + c];
          float x0 = (base + 0 + h < s1) ? __int_as_float(t0.y) : 0.f;
          float x1 = (base + 2 + h < s1) ? __int_as_float(t1_.y) : 0.f;
          float x2 = (base + 4 + h < s1) ? __int_as_float(t2.y) : 0.f;
          float x3 = (base + 6 + h < s1) ? __int_as_float(t3.y) : 0.f;
          a0 = fmaf(x0, blo(u0), a0); a1 = fmaf(x0, bhi(u0), a1);
          a0 = fmaf(x1, blo(u1), a0); a1 = fmaf(x1, bhi(u1), a1);
          a0 = fmaf(x2, blo(u2), a0); a1 = fmaf(x2, bhi(u2), a1);
          a0 = fmaf(x3, blo(u3), a0); a1 = fmaf(x3, bhi(u3), a1);
        }
      }
      a0 += __shfl_xor(a0, 32, 64);
      a1 += __shfl_xor(a1, 32, 64);
      if (h == 0) *reinterpret_cast<unsigned int*>(&t1s[wv][rr][2 * c]) = pack2(a0, a1);
      q0 = n0; q1 = n1; q2 = n2; q3 = n3;
    }
  }
  // wave-local LDS write->read: compiler inserts lgkmcnt wait; no barrier needed.

  // ================= MFMA phase =================
  const int g = l >> 4;    // A: k-group; D: row-group
  const int li = l & 15;   // A: row; D: col
  const int r = rbase + li;

  bf16x8 A0 = *reinterpret_cast<const bf16x8*>(&t1s[wv][li][8 * g]);       // t1 k 0..31 slice
  bf16x8 A1 = *reinterpret_cast<const bf16x8*>(&t1s[wv][li][32 + 8 * g]);  // t1 k 32..63 slice
  const unsigned short* __restrict__ eb = reinterpret_cast<const unsigned short*>(ebf);
  bf16x8 E0 = *reinterpret_cast<const bf16x8*>(eb + (size_t)r * 64 + 8 * g);
  bf16x8 E1 = *reinterpret_cast<const bf16x8*>(eb + (size_t)r * 64 + 32 + 8 * g);
  bf16x8 T0 = mulbf8(A0, E0);
  bf16x8 T1 = mulbf8(A1, E1);

  const float* __restrict__ bsl = bs + (size_t)layer * 3 * 64;
  f32x4 acc[4];
#pragma unroll
  for (int f = 0; f < 4; ++f) {
    int n = f * 16 + li;
    float bv = bsl[n] + bsl[64 + n] + bsl[128 + n];
    acc[f] = (f32x4){bv, bv, bv, bv};
  }

  bf16x8 Afr[6] = {A0, A1, T0, T1, E0, E1};
#pragma unroll
  for (int s = 0; s < 6; ++s) {
#pragma unroll
    for (int f = 0; f < 4; ++f) {
      const bf16x8 Bf = *reinterpret_cast<const bf16x8*>(&Bt[f * 16 + li][s * 32 + 8 * g]);
      acc[f] = __builtin_amdgcn_mfma_f32_16x16x32_bf16(Afr[s], Bf, acc[f], 0, 0, 0);
    }
  }

  // epilogue: leaky relu, row L2 norm (row = rbase + 4*g + reg, col = f*16 + li)
  float p[4];
#pragma unroll
  for (int reg = 0; reg < 4; ++reg) {
    float ssum = 0.f;
#pragma unroll
    for (int f = 0; f < 4; ++f) {
      float x = acc[f][reg];
      x = (x >= 0.f) ? x : 0.01f * x;
      acc[f][reg] = x;
      ssum = fmaf(x, x, ssum);
    }
    p[reg] = ssum;
  }
#pragma unroll
  for (int off = 1; off < 16; off <<= 1) {
#pragma unroll
    for (int reg = 0; reg < 4; ++reg) p[reg] += __shfl_xor(p[reg], off, 64);
  }
  float inv[4];
#pragma unroll
  for (int reg = 0; reg < 4; ++reg) inv[reg] = 1.0f / fmaxf(sqrtf(p[reg]), 1e-12f);

  float* __restrict__ ob = out + (size_t)(layer + 1) * 64;
#pragma unroll
  for (int reg = 0; reg < 4; ++reg) {
#pragma unroll
    for (int f = 0; f < 4; ++f) {
      float val = acc[f][reg] * inv[reg];
      ob[(size_t)(rbase + 4 * g + reg) * 256 + f * 16 + li] = val;
      if (wbf) ebf_next[(size_t)(rbase + 4 * g + reg) * 64 + f * 16 + li] = f2b(val);
    }
  }
}

extern "C" void kernel_launch(void* const* d_in, const int* in_sizes, int n_in,
                              void* d_out, int out_size, void* d_ws, size_t ws_size,
                              hipStream_t stream) {
  const int* edge_src = (const int*)d_in[0];
  const int* edge_dst = (const int*)d_in[1];
  const float* edge_w = (const float*)d_in[2];
  const float* user_emb = (const float*)d_in[3];
  const float* item_emb = (const float*)d_in[4];
  const float* Ws = (const float*)d_in[5];
  const float* bs = (const float*)d_in[6];
  float* out = (float*)d_out;

  char* w = (char*)d_ws;
  unsigned int* ebfA = (unsigned int*)w; w += (size_t)NN * 32 * 4;  // 25.6 MB
  unsigned int* ebfB = (unsigned int*)w; w += (size_t)NN * 32 * 4;  // 25.6 MB
  int2* csr_pack = (int2*)w;      w += (size_t)NE * 8;              // 10 MB
  int* cnt = (int*)w;             w += (size_t)NN * 4;
  int* local = (int*)w;           w += (size_t)NN * 4;
  int* row_start = (int*)w;       w += (size_t)(NN + 4) * 4;
  int* cursor = (int*)w;          w += (size_t)NN * 4;
  int* btot = (int*)w;            w += 256 * 4;

  k_zero<<<(NN + 255) / 256, 256, 0, stream>>>(cnt);
  k_init<<<(NN * 16 + 255) / 256, 256, 0, stream>>>(
      (const float4*)user_emb, (const float4*)item_emb, (float4*)out, (uint2*)ebfA);
  k_hist<<<(NE + 255) / 256, 256, 0, stream>>>(edge_dst, cnt);
  k_scan1<<<NB, SCAN_B, 0, stream>>>(cnt, local, btot);
  k_scan2<<<1, 256, 0, stream>>>(btot);
  k_finalize<<<(NN + 255) / 256, 256, 0, stream>>>(local, btot, row_start, cursor);
  k_fill<<<(NE + 255) / 256, 256, 0, stream>>>(edge_src, edge_dst, edge_w, cursor, csr_pack);

  // layer 0: read ebfA -> write ebfB; layer 1: read ebfB -> write ebfA; layer 2: read ebfA
  k_layer<<<NN / 64, 256, 0, stream>>>(row_start, csr_pack, ebfA, Ws, bs, out,
                                       (unsigned short*)ebfB, 0, 1);
  k_layer<<<NN / 64, 256, 0, stream>>>(row_start, csr_pack, ebfB, Ws, bs, out,
                                       (unsigned short*)ebfA, 1, 1);
  k_layer<<<NN / 64, 256, 0, stream>>>(row_start, csr_pack, ebfA, Ws, bs, out,
                                       (unsigned short*)ebfB, 2, 0);
}

// Round 5
// 415.568 us; speedup vs baseline: 2.6909x; 1.0012x over previous
//
#include <hip/hip_runtime.h>
#include <hip/hip_bf16.h>

#define NU 50000
#define NI 150000
#define NN 200000
#define NE 1250000
#define DD 64
#define NLAYERS 3
#define SCAN_B 1024
#define NB ((NN + SCAN_B - 1) / SCAN_B)   // 196
#define BT_STRIDE 232                      // bf16; 464B row: 16B-aligned, <=2-way banks

typedef __attribute__((ext_vector_type(8))) short bf16x8;
typedef __attribute__((ext_vector_type(4))) float f32x4;

static __device__ __forceinline__ unsigned short f2b(float x) {
  __hip_bfloat16 h = __float2bfloat16(x);  // RNE
  return *reinterpret_cast<unsigned short*>(&h);
}

static __device__ __forceinline__ unsigned int pack2(float lo, float hi) {
  return (unsigned int)f2b(lo) | ((unsigned int)f2b(hi) << 16);
}

static __device__ __forceinline__ float blo(unsigned int u) { return __uint_as_float(u << 16); }
static __device__ __forceinline__ float bhi(unsigned int u) { return __uint_as_float(u & 0xffff0000u); }

// elementwise bf16x8 * bf16x8 -> bf16x8 (via f32)
static __device__ __forceinline__ bf16x8 mulbf8(bf16x8 a, bf16x8 b) {
  union { bf16x8 v; unsigned int u[4]; } A, B, R;
  A.v = a; B.v = b;
#pragma unroll
  for (int i = 0; i < 4; ++i) {
    R.u[i] = pack2(blo(A.u[i]) * blo(B.u[i]), bhi(A.u[i]) * bhi(B.u[i]));
  }
  return R.v;
}

// ---- zero cnt (in-graph hipMemsetAsync was ~118us; this is ~2us) ----
__global__ __launch_bounds__(256) void k_zero(int* __restrict__ p) {
  int i = blockIdx.x * 256 + threadIdx.x;
  if (i < NN) p[i] = 0;
}

// ---- init: out[:, 0:64] = concat(user_emb, item_emb); also bf16 copy ----
__global__ __launch_bounds__(256) void k_init(const float4* __restrict__ ue,
                                              const float4* __restrict__ ie,
                                              float4* __restrict__ out4,
                                              uint2* __restrict__ ebf2) {
  int gid = blockIdx.x * 256 + threadIdx.x;
  if (gid >= NN * 16) return;
  int row = gid >> 4, q = gid & 15;
  float4 v = (row < NU) ? ue[(size_t)row * 16 + q] : ie[(size_t)(row - NU) * 16 + q];
  out4[(size_t)row * 64 + q] = v;  // out row stride = 256 floats = 64 float4
  uint2 b; b.x = pack2(v.x, v.y); b.y = pack2(v.z, v.w);
  ebf2[(size_t)row * 16 + q] = b;  // ebf row = 64 bf16 = 16 uint2
}

// ---- CSR build ----
__global__ __launch_bounds__(256) void k_hist(const int* __restrict__ dst, int* __restrict__ cnt) {
  int e = blockIdx.x * 256 + threadIdx.x;
  if (e < NE) atomicAdd(&cnt[dst[e]], 1);
}

__global__ __launch_bounds__(SCAN_B) void k_scan1(const int* __restrict__ cnt,
                                                  int* __restrict__ local,
                                                  int* __restrict__ btot) {
  __shared__ int sm[SCAN_B];
  int t = threadIdx.x;
  int i = blockIdx.x * SCAN_B + t;
  int v = (i < NN) ? cnt[i] : 0;
  sm[t] = v;
  __syncthreads();
  for (int off = 1; off < SCAN_B; off <<= 1) {
    int x = (t >= off) ? sm[t - off] : 0;
    __syncthreads();
    sm[t] += x;
    __syncthreads();
  }
  if (i < NN) local[i] = sm[t] - v;              // exclusive within block
  if (t == SCAN_B - 1) btot[blockIdx.x] = sm[t]; // block total
}

__global__ __launch_bounds__(256) void k_scan2(int* __restrict__ btot) {
  __shared__ int sm[256];
  int t = threadIdx.x;
  int v = (t < NB) ? btot[t] : 0;
  sm[t] = v;
  __syncthreads();
  for (int off = 1; off < 256; off <<= 1) {
    int x = (t >= off) ? sm[t - off] : 0;
    __syncthreads();
    sm[t] += x;
    __syncthreads();
  }
  if (t < NB) btot[t] = sm[t] - v;  // exclusive block offsets
}

__global__ __launch_bounds__(256) void k_finalize(const int* __restrict__ local,
                                                  const int* __restrict__ btot,
                                                  int* __restrict__ row_start,
                                                  int* __restrict__ cursor) {
  int i = blockIdx.x * 256 + threadIdx.x;
  if (i < NN) {
    int v = local[i] + btot[i / SCAN_B];
    row_start[i] = v;
    cursor[i] = v;
  }
  if (i == 0) row_start[NN] = NE;
}

__global__ __launch_bounds__(256) void k_fill(const int* __restrict__ src,
                                              const int* __restrict__ dst,
                                              const float* __restrict__ w,
                                              int* __restrict__ cursor,
                                              int2* __restrict__ csr_pack) {
  int e = blockIdx.x * 256 + threadIdx.x;
  if (e < NE) {
    int p = atomicAdd(&cursor[dst[e]], 1);
    int2 pk; pk.x = src[e]; pk.y = __float_as_int(w[e]);
    csr_pack[p] = pk;
  }
}

// ---- SpMM: one wave per row; lane = 32*h + c; clamped 8-edge rounds; bf16 out ----
__global__ __launch_bounds__(256) void k_spmm(const int* __restrict__ row_start,
                                              const int2* __restrict__ csr_pack,
                                              const unsigned int* __restrict__ ebf, // [NN][32] uint (64 bf16)
                                              unsigned int* __restrict__ t1bf) {   // [NN][32] uint (64 bf16)
  int gid = blockIdx.x * 256 + threadIdx.x;
  int row = gid >> 6;
  if (row >= NN) return;
  int l = gid & 63;
  int h = l >> 5;   // which edge of the pair
  int c = l & 31;   // col-pair index: cols 2c, 2c+1
  int s0 = row_start[row];
  int s1 = row_start[row + 1];
  float a0 = 0.f, a1 = 0.f;
  for (int base = s0; base < s1; base += 8) {
    int j0 = base + 0 + h, j1 = base + 2 + h, j2 = base + 4 + h, j3 = base + 6 + h;
    int2 p0 = csr_pack[j0 < s1 ? j0 : 0];
    int2 p1 = csr_pack[j1 < s1 ? j1 : 0];
    int2 p2 = csr_pack[j2 < s1 ? j2 : 0];
    int2 p3 = csr_pack[j3 < s1 ? j3 : 0];
    unsigned int v0 = ebf[(size_t)p0.x * 32 + c];
    unsigned int v1 = ebf[(size_t)p1.x * 32 + c];
    unsigned int v2 = ebf[(size_t)p2.x * 32 + c];
    unsigned int v3 = ebf[(size_t)p3.x * 32 + c];
    float w0 = (j0 < s1) ? __int_as_float(p0.y) : 0.f;
    float w1 = (j1 < s1) ? __int_as_float(p1.y) : 0.f;
    float w2 = (j2 < s1) ? __int_as_float(p2.y) : 0.f;
    float w3 = (j3 < s1) ? __int_as_float(p3.y) : 0.f;
    a0 = fmaf(w0, blo(v0), a0); a1 = fmaf(w0, bhi(v0), a1);
    a0 = fmaf(w1, blo(v1), a0); a1 = fmaf(w1, bhi(v1), a1);
    a0 = fmaf(w2, blo(v2), a0); a1 = fmaf(w2, bhi(v2), a1);
    a0 = fmaf(w3, blo(v3), a0); a1 = fmaf(w3, bhi(v3), a1);
  }
  a0 += __shfl_xor(a0, 32, 64);
  a1 += __shfl_xor(a1, 32, 64);
  if (h == 0) t1bf[(size_t)row * 32 + c] = pack2(a0, a1);
}

// ---- GEMM via MFMA: inter = [t1 | t1*e | e] @ [W1;W2;W3] + b; leaky; l2norm ----
// wave = 16 rows; block = 4 waves = 64 rows; grid = 3125
__global__ __launch_bounds__(256) void k_row_mfma(const unsigned int* __restrict__ t1bf,
                                                  const unsigned int* __restrict__ ebf,
                                                  const float* __restrict__ Ws,
                                                  const float* __restrict__ bs,
                                                  float* __restrict__ out,
                                                  unsigned short* __restrict__ ebf_next,
                                                  int layer, int wbf) {
  __shared__ unsigned short Bt[64][BT_STRIDE];  // Bt[n][j] = bf16(Wcat[j][n]), j in [0,192)
  const int tid = threadIdx.x;
  const float* __restrict__ Wl = Ws + (size_t)layer * 3 * 4096;
  {
    int n = tid & 63;
    int jb = (tid >> 6) * 48;
#pragma unroll 4
    for (int j = jb; j < jb + 48; ++j) Bt[n][j] = f2b(Wl[(size_t)j * 64 + n]);
  }
  __syncthreads();

  const int l = tid & 63;
  const int wv = tid >> 6;
  const int g = l >> 4;    // A: k-group; D: row-group
  const int li = l & 15;   // A: row; D: col
  const int rowbase = blockIdx.x * 64 + wv * 16;
  const int r = rowbase + li;

  // A fragments straight from bf16 buffers: lane holds 8 contiguous k at 8*g / 32+8*g
  const unsigned short* __restrict__ t1b = reinterpret_cast<const unsigned short*>(t1bf);
  const unsigned short* __restrict__ eb = reinterpret_cast<const unsigned short*>(ebf);
  bf16x8 A0 = *reinterpret_cast<const bf16x8*>(t1b + (size_t)r * 64 + 8 * g);
  bf16x8 A1 = *reinterpret_cast<const bf16x8*>(t1b + (size_t)r * 64 + 32 + 8 * g);
  bf16x8 E0 = *reinterpret_cast<const bf16x8*>(eb + (size_t)r * 64 + 8 * g);
  bf16x8 E1 = *reinterpret_cast<const bf16x8*>(eb + (size_t)r * 64 + 32 + 8 * g);
  bf16x8 T0 = mulbf8(A0, E0);
  bf16x8 T1 = mulbf8(A1, E1);

  const float* __restrict__ bsl = bs + (size_t)layer * 3 * 64;
  f32x4 acc[4];
#pragma unroll
  for (int f = 0; f < 4; ++f) {
    int n = f * 16 + li;
    float bv = bsl[n] + bsl[64 + n] + bsl[128 + n];
    acc[f] = (f32x4){bv, bv, bv, bv};
  }

  bf16x8 Afr[6] = {A0, A1, T0, T1, E0, E1};
#pragma unroll
  for (int s = 0; s < 6; ++s) {
#pragma unroll
    for (int f = 0; f < 4; ++f) {
      const bf16x8 Bf = *reinterpret_cast<const bf16x8*>(&Bt[f * 16 + li][s * 32 + 8 * g]);
      acc[f] = __builtin_amdgcn_mfma_f32_16x16x32_bf16(Afr[s], Bf, acc[f], 0, 0, 0);
    }
  }

  // epilogue: leaky relu, row L2 norm (row = rowbase + 4*g + reg, col = f*16 + li)
  float p[4];
#pragma unroll
  for (int reg = 0; reg < 4; ++reg) {
    float ssum = 0.f;
#pragma unroll
    for (int f = 0; f < 4; ++f) {
      float x = acc[f][reg];
      x = (x >= 0.f) ? x : 0.01f * x;
      acc[f][reg] = x;
      ssum = fmaf(x, x, ssum);
    }
    p[reg] = ssum;
  }
#pragma unroll
  for (int off = 1; off < 16; off <<= 1) {
#pragma unroll
    for (int reg = 0; reg < 4; ++reg) p[reg] += __shfl_xor(p[reg], off, 64);
  }
  float inv[4];
#pragma unroll
  for (int reg = 0; reg < 4; ++reg) inv[reg] = 1.0f / fmaxf(sqrtf(p[reg]), 1e-12f);

  float* __restrict__ ob = out + (size_t)(layer + 1) * 64;
#pragma unroll
  for (int reg = 0; reg < 4; ++reg) {
#pragma unroll
    for (int f = 0; f < 4; ++f) {
      float val = acc[f][reg] * inv[reg];
      ob[(size_t)(rowbase + 4 * g + reg) * 256 + f * 16 + li] = val;
      if (wbf) ebf_next[(size_t)(rowbase + 4 * g + reg) * 64 + f * 16 + li] = f2b(val);
    }
  }
}

extern "C" void kernel_launch(void* const* d_in, const int* in_sizes, int n_in,
                              void* d_out, int out_size, void* d_ws, size_t ws_size,
                              hipStream_t stream) {
  const int* edge_src = (const int*)d_in[0];
  const int* edge_dst = (const int*)d_in[1];
  const float* edge_w = (const float*)d_in[2];
  const float* user_emb = (const float*)d_in[3];
  const float* item_emb = (const float*)d_in[4];
  const float* Ws = (const float*)d_in[5];
  const float* bs = (const float*)d_in[6];
  float* out = (float*)d_out;

  char* w = (char*)d_ws;
  unsigned int* ebfA = (unsigned int*)w; w += (size_t)NN * 32 * 4;  // 25.6 MB
  unsigned int* ebfB = (unsigned int*)w; w += (size_t)NN * 32 * 4;  // 25.6 MB
  unsigned int* t1bf = (unsigned int*)w; w += (size_t)NN * 32 * 4;  // 25.6 MB
  int2* csr_pack = (int2*)w;      w += (size_t)NE * 8;              // 10 MB
  int* cnt = (int*)w;             w += (size_t)NN * 4;
  int* local = (int*)w;           w += (size_t)NN * 4;
  int* row_start = (int*)w;       w += (size_t)(NN + 4) * 4;
  int* cursor = (int*)w;          w += (size_t)NN * 4;
  int* btot = (int*)w;            w += 256 * 4;

  k_zero<<<(NN + 255) / 256, 256, 0, stream>>>(cnt);
  k_init<<<(NN * 16 + 255) / 256, 256, 0, stream>>>(
      (const float4*)user_emb, (const float4*)item_emb, (float4*)out, (uint2*)ebfA);
  k_hist<<<(NE + 255) / 256, 256, 0, stream>>>(edge_dst, cnt);
  k_scan1<<<NB, SCAN_B, 0, stream>>>(cnt, local, btot);
  k_scan2<<<1, 256, 0, stream>>>(btot);
  k_finalize<<<(NN + 255) / 256, 256, 0, stream>>>(local, btot, row_start, cursor);
  k_fill<<<(NE + 255) / 256, 256, 0, stream>>>(edge_src, edge_dst, edge_w, cursor, csr_pack);

  // layer l reads ebfX, writes ebfY (double-buffered to avoid cross-block races)
  k_spmm<<<(NN * 64 + 255) / 256, 256, 0, stream>>>(row_start, csr_pack, ebfA, t1bf);
  k_row_mfma<<<NN / 64, 256, 0, stream>>>(t1bf, ebfA, Ws, bs, out, (unsigned short*)ebfB, 0, 1);
  k_spmm<<<(NN * 64 + 255) / 256, 256, 0, stream>>>(row_start, csr_pack, ebfB, t1bf);
  k_row_mfma<<<NN / 64, 256, 0, stream>>>(t1bf, ebfB, Ws, bs, out, (unsigned short*)ebfA, 1, 1);
  k_spmm<<<(NN * 64 + 255) / 256, 256, 0, stream>>>(row_start, csr_pack, ebfA, t1bf);
  k_row_mfma<<<NN / 64, 256, 0, stream>>>(t1bf, ebfA, Ws, bs, out, (unsigned short*)ebfB, 2, 0);
}